// Round 1
// baseline (153.699 us; speedup 1.0000x reference)
//
#include <hip/hip_runtime.h>

#define NSEQ 2048
#define DH 64
#define NH 16
#define BQ 64
#define BKV 64
#define LP 72   // LDS row stride in bf16 elems (padded vs 64 to break bank conflicts)

typedef __attribute__((ext_vector_type(8))) short bf16x8;
typedef __attribute__((ext_vector_type(4))) float f32x4;

static __device__ __forceinline__ short f2bf(float f) {
    unsigned u = __float_as_uint(f);
    u += 0x7fffu + ((u >> 16) & 1u);   // round-to-nearest-even
    return (short)(u >> 16);
}

// ---------------- gating ----------------
__global__ void gate_partial(const float* __restrict__ gi, float* __restrict__ wsA) {
    int b = blockIdx.x >> 3, sl = blockIdx.x & 7;
    int tid = threadIdx.x;
    int g = tid & 127, half = tid >> 7;
    float s = 0.f;
    int n0 = sl * 256;
    for (int n = n0 + half; n < n0 + 256; n += 2)
        s += gi[((size_t)b * NSEQ + n) * 128 + g];
    __shared__ float part[2][128];
    part[half][g] = s;
    __syncthreads();
    if (tid < 128) wsA[(b * 8 + sl) * 128 + tid] = part[0][tid] + part[1][tid];
}

__global__ void gate_final(const float* __restrict__ wsA, const float* __restrict__ Wg,
                           const float* __restrict__ bg, float* __restrict__ ws_sm,
                           int* __restrict__ ws_idx) {
    int b = blockIdx.x, tid = threadIdx.x;
    __shared__ float meanv[128];
    __shared__ float logits[NH];
    if (tid < 128) {
        float s = 0.f;
        for (int sl = 0; sl < 8; ++sl) s += wsA[(b * 8 + sl) * 128 + tid];
        meanv[tid] = s * (1.0f / NSEQ);
    }
    __syncthreads();
    if (tid < 128) {
        int h = tid >> 3, j = tid & 7;
        float p = 0.f;
        for (int i = 0; i < 16; ++i) { int g = j + 8 * i; p += meanv[g] * Wg[h * 128 + g]; }
        p += __shfl_xor(p, 1);
        p += __shfl_xor(p, 2);
        p += __shfl_xor(p, 4);
        if (j == 0) logits[h] = p + bg[h];
    }
    __syncthreads();
    if (tid == 0) {
        float mx = logits[0];
        for (int h = 1; h < NH; ++h) mx = fmaxf(mx, logits[h]);
        float e[NH], sum = 0.f;
        for (int h = 0; h < NH; ++h) { e[h] = __expf(logits[h] - mx); sum += e[h]; }
        float inv = 1.0f / sum;
        for (int h = 0; h < NH; ++h) ws_sm[b * NH + h] = e[h] * inv;
        int i1 = 0;
        for (int h = 1; h < NH; ++h) if (logits[h] > logits[i1]) i1 = h;
        int i2 = (i1 == 0) ? 1 : 0;
        for (int h = 0; h < NH; ++h) if (h != i1 && logits[h] > logits[i2]) i2 = h;
        ws_idx[b * 2 + 0] = i1;
        ws_idx[b * 2 + 1] = i2;
    }
}

__global__ void lb_kernel(const float* __restrict__ ws_sm, const int* __restrict__ ws_idx,
                          float* __restrict__ out_lb) {
    if (threadIdx.x == 0 && blockIdx.x == 0) {
        float counts[NH];
        for (int h = 0; h < NH; ++h) counts[h] = 0.f;
        for (int i = 0; i < 16; ++i) counts[ws_idx[i]] += 1.0f;
        float lb = 0.f;
        for (int h = 0; h < NH; ++h) {
            float msm = 0.f;
            for (int b = 0; b < 8; ++b) msm += ws_sm[b * NH + h];
            msm *= (1.0f / 8.0f);
            lb += msm * (counts[h] / (16.0f + 1e-6f));
        }
        out_lb[0] = lb * (float)NH;
    }
}

// ---------------- attention ----------------
__global__ __launch_bounds__(256, 2)
void attn_kernel(const float* __restrict__ q, const float* __restrict__ k,
                 const float* __restrict__ v, const float* __restrict__ mask,
                 const int* __restrict__ topk, float* __restrict__ out) {
    const int qt = blockIdx.x;   // 0..31
    const int kk = blockIdx.y;   // 0..1
    const int b  = blockIdx.z;   // 0..7
    const int h  = topk[b * 2 + kk];
    const int tid = threadIdx.x;
    const int wave = tid >> 6;
    const int lane = tid & 63;
    const int lr = lane & 15;    // row-in-16 (A) / col (B, C/D)
    const int lg = lane >> 4;    // k-chunk group 0..3

    __shared__ short Kb[BKV][LP];     // K tile, bf16 row-major [n][d]
    __shared__ short Vt[DH][LP];      // V tile transposed, [d][n]
    __shared__ short Pl[4][16][LP];   // per-wave P tile [qrow16][n64]

    const float QSC = 0.125f * 1.4426950408889634f; // 1/sqrt(64) * log2(e)
    const float MSC = 1.4426950408889634f;          // log2(e) for the mask add

    const size_t headoff = ((size_t)b * NH + h) * (size_t)NSEQ * DH;

    // Q fragments: lane holds q[row=lr][d = f*32 + lg*8 + j], scaled
    bf16x8 qf[2];
    {
        const float* qp = q + headoff + (size_t)(qt * BQ + wave * 16 + lr) * DH;
        for (int f = 0; f < 2; ++f) {
            const float* p = qp + f * 32 + lg * 8;
            float4 a = *(const float4*)p;
            float4 c = *(const float4*)(p + 4);
            qf[f][0] = f2bf(a.x * QSC); qf[f][1] = f2bf(a.y * QSC);
            qf[f][2] = f2bf(a.z * QSC); qf[f][3] = f2bf(a.w * QSC);
            qf[f][4] = f2bf(c.x * QSC); qf[f][5] = f2bf(c.y * QSC);
            qf[f][6] = f2bf(c.z * QSC); qf[f][7] = f2bf(c.w * QSC);
        }
    }

    f32x4 acc[4];
    float m_r[4], l_r[4];
    for (int dt = 0; dt < 4; ++dt)
        for (int r = 0; r < 4; ++r) acc[dt][r] = 0.f;
    for (int r = 0; r < 4; ++r) { m_r[r] = -INFINITY; l_r[r] = 0.f; }

    const float* kb = k + headoff;
    const float* vb = v + headoff;
    const float* mb = mask + (size_t)b * NSEQ * NSEQ + (size_t)(qt * BQ + wave * 16) * NSEQ;

    const int srow = tid >> 4;        // staging row 0..15
    const int scol = (tid & 15) * 4;  // staging col 0,4..60

    for (int t0 = 0; t0 < NSEQ; t0 += BKV) {
        __syncthreads();  // previous iter's LDS reads done before overwrite
        for (int pp = 0; pp < 4; ++pp) {
            int n = pp * 16 + srow;
            float4 k4 = *(const float4*)(kb + (size_t)(t0 + n) * DH + scol);
            *(short4*)&Kb[n][scol] = make_short4(f2bf(k4.x), f2bf(k4.y), f2bf(k4.z), f2bf(k4.w));
            float4 v4 = *(const float4*)(vb + (size_t)(t0 + n) * DH + scol);
            Vt[scol + 0][n] = f2bf(v4.x);
            Vt[scol + 1][n] = f2bf(v4.y);
            Vt[scol + 2][n] = f2bf(v4.z);
            Vt[scol + 3][n] = f2bf(v4.w);
        }
        __syncthreads();

        // S = (q/8*log2e) . K^T  -> per lane 4 col-tiles x 4 rows
        f32x4 s[4];
        for (int ct = 0; ct < 4; ++ct) {
            bf16x8 kf0 = *(const bf16x8*)&Kb[ct * 16 + lr][lg * 8];
            bf16x8 kf1 = *(const bf16x8*)&Kb[ct * 16 + lr][32 + lg * 8];
            f32x4 z; for (int r = 0; r < 4; ++r) z[r] = 0.f;
            z = __builtin_amdgcn_mfma_f32_16x16x32_bf16(qf[0], kf0, z, 0, 0, 0);
            z = __builtin_amdgcn_mfma_f32_16x16x32_bf16(qf[1], kf1, z, 0, 0, 0);
            s[ct] = z;
        }
        // mask add (log2 domain): C/D layout row=4*lg+r, col=ct*16+lr
        for (int r = 0; r < 4; ++r) {
            const float* mp = mb + (size_t)(4 * lg + r) * NSEQ + t0 + lr;
            for (int ct = 0; ct < 4; ++ct)
                s[ct][r] = fmaf(mp[ct * 16], MSC, s[ct][r]);
        }
        // online softmax (log2 domain), row lives in one 16-lane group
        float mnew[4], sc[4], ps[4];
        for (int r = 0; r < 4; ++r) {
            float tm = fmaxf(fmaxf(s[0][r], s[1][r]), fmaxf(s[2][r], s[3][r]));
            tm = fmaxf(tm, __shfl_xor(tm, 1));
            tm = fmaxf(tm, __shfl_xor(tm, 2));
            tm = fmaxf(tm, __shfl_xor(tm, 4));
            tm = fmaxf(tm, __shfl_xor(tm, 8));
            mnew[r] = fmaxf(m_r[r], tm);
            sc[r] = __builtin_amdgcn_exp2f(m_r[r] - mnew[r]);
            ps[r] = 0.f;
        }
        for (int ct = 0; ct < 4; ++ct) {
            for (int r = 0; r < 4; ++r) {
                float p = __builtin_amdgcn_exp2f(s[ct][r] - mnew[r]);
                ps[r] += p;
                Pl[wave][4 * lg + r][ct * 16 + lr] = f2bf(p);
            }
        }
        for (int r = 0; r < 4; ++r) {
            float t = ps[r];
            t += __shfl_xor(t, 1);
            t += __shfl_xor(t, 2);
            t += __shfl_xor(t, 4);
            t += __shfl_xor(t, 8);
            l_r[r] = l_r[r] * sc[r] + t;
            m_r[r] = mnew[r];
        }
        for (int dt = 0; dt < 4; ++dt)
            for (int r = 0; r < 4; ++r) acc[dt][r] *= sc[r];

        // PV: A = P (same-wave LDS round trip, compiler orders via lgkmcnt)
        bf16x8 pf0 = *(const bf16x8*)&Pl[wave][lr][lg * 8];
        bf16x8 pf1 = *(const bf16x8*)&Pl[wave][lr][32 + lg * 8];
        for (int dt = 0; dt < 4; ++dt) {
            bf16x8 vf0 = *(const bf16x8*)&Vt[dt * 16 + lr][lg * 8];
            bf16x8 vf1 = *(const bf16x8*)&Vt[dt * 16 + lr][32 + lg * 8];
            acc[dt] = __builtin_amdgcn_mfma_f32_16x16x32_bf16(pf0, vf0, acc[dt], 0, 0, 0);
            acc[dt] = __builtin_amdgcn_mfma_f32_16x16x32_bf16(pf1, vf1, acc[dt], 0, 0, 0);
        }
    }

    for (int r = 0; r < 4; ++r) {
        float inv = 1.0f / l_r[r];
        int qrow = qt * BQ + wave * 16 + 4 * lg + r;
        float* op = out + ((size_t)b * NSEQ + qrow) * 128 + kk * 64;
        for (int dt = 0; dt < 4; ++dt) op[dt * 16 + lr] = acc[dt][r] * inv;
    }
}

extern "C" void kernel_launch(void* const* d_in, const int* in_sizes, int n_in,
                              void* d_out, int out_size, void* d_ws, size_t ws_size,
                              hipStream_t stream) {
    const float* q    = (const float*)d_in[0];
    const float* k    = (const float*)d_in[1];
    const float* v    = (const float*)d_in[2];
    const float* gi   = (const float*)d_in[3];
    const float* mask = (const float*)d_in[4];
    const float* Wg   = (const float*)d_in[5];
    const float* bg   = (const float*)d_in[6];
    float* out = (float*)d_out;

    float* wsA   = (float*)d_ws;          // 8*8*128 partial sums
    float* ws_sm = wsA + 8 * 8 * 128;     // 8*16 softmax
    int*   ws_idx = (int*)(ws_sm + 8 * NH); // 16 ints

    gate_partial<<<64, 256, 0, stream>>>(gi, wsA);
    gate_final<<<8, 256, 0, stream>>>(wsA, Wg, bg, ws_sm, ws_idx);
    lb_kernel<<<1, 64, 0, stream>>>(ws_sm, ws_idx, out + (size_t)8 * NSEQ * 128);

    dim3 grid(NSEQ / BQ, 2, 8);
    attn_kernel<<<grid, 256, 0, stream>>>(q, k, v, mask, ws_idx, out);
}